// Round 8
// baseline (334.603 us; speedup 1.0000x reference)
//
#include <hip/hip_runtime.h>
#include <hip/hip_fp16.h>
#include <math.h>

#define D_IN   128
#define H_DIM  32
#define OUT_DIM 3

#define BS      512          // nodes per bucket (pow2)
#define LOGBS   9
#define CAP     18432        // max edges per bucket slice in LDS
#define EPB     2048         // edges per block, k_bcount
#define EPB_P   4096         // edges per block, k_part
#define NB_MAX  1024

static __device__ inline unsigned int h2u(__half2 h) {
    union { __half2 h; unsigned int u; } c; c.h = h; return c.u;
}
static __device__ inline __half2 u2h(unsigned int u) {
    union { unsigned int u; __half2 h; } c; c.u = u; return c.h;
}
static __device__ inline __half2 sh2(__half2 v, int o) {
    return u2h((unsigned int)__shfl_xor((int)h2u(v), o));
}

// ---------------- tiny zero ----------------

__global__ void k_zero(int* p, int n) {
    int i = blockIdx.x * blockDim.x + threadIdx.x;
    if (i < n) p[i] = 0;
}

// ---------------- bucket count ----------------

__global__ __launch_bounds__(256) void k_bcount(
    const int* __restrict__ dst, int* __restrict__ bcnt, int e, int nb)
{
    __shared__ int hist[NB_MAX];
    const int t = threadIdx.x;
    for (int j = t; j < nb; j += 256) hist[j] = 0;
    __syncthreads();
    const int base = blockIdx.x * EPB;
#pragma unroll
    for (int k = 0; k < EPB / 256; ++k) {
        int i = base + k * 256 + t;
        if (i < e) atomicAdd(&hist[dst[i] >> LOGBS], 1);
    }
    __syncthreads();
    for (int j = t; j < nb; j += 256)
        if (hist[j]) atomicAdd(&bcnt[j], hist[j]);
}

// ---------------- bucket scan (single block) ----------------

__global__ __launch_bounds__(256) void k_bscan(
    const int* __restrict__ bcnt, int* __restrict__ boff, int* __restrict__ bcur,
    int* __restrict__ offs, int nb, int n, int e)
{
    __shared__ int ss[256];
    const int t = threadIdx.x;
    int v[4];
    int loc = 0;
#pragma unroll
    for (int k = 0; k < 4; ++k) {
        int j = t * 4 + k;
        v[k] = (j < nb) ? bcnt[j] : 0;
        loc += v[k];
    }
    ss[t] = loc;
    __syncthreads();
    for (int off = 1; off < 256; off <<= 1) {
        int u = (t >= off) ? ss[t - off] : 0;
        __syncthreads();
        ss[t] += u;
        __syncthreads();
    }
    int base = ss[t] - loc;
#pragma unroll
    for (int k = 0; k < 4; ++k) {
        int j = t * 4 + k;
        if (j < nb) { boff[j] = base; bcur[j] = base; base += v[k]; }
    }
    if (t == 0) { boff[nb] = e; offs[n] = e; }
}

// ---------------- partition: packed edges into bucket regions ------
// pack = src | ((dst & (BS-1)) << 17)

__global__ __launch_bounds__(256) void k_part(
    const int* __restrict__ src, const int* __restrict__ dst,
    int* __restrict__ bcur, int* __restrict__ tmp, int e, int nb)
{
    __shared__ int hist[NB_MAX];
    __shared__ int cur[NB_MAX];
    const int t = threadIdx.x;
    for (int j = t; j < nb; j += 256) hist[j] = 0;
    __syncthreads();

    const int base = blockIdx.x * EPB_P;
    int d[EPB_P / 256], s[EPB_P / 256];
#pragma unroll
    for (int k = 0; k < EPB_P / 256; ++k) {
        int i = base + k * 256 + t;
        if (i < e) {
            d[k] = dst[i];
            s[k] = src[i];
            atomicAdd(&hist[d[k] >> LOGBS], 1);
        } else d[k] = -1;
    }
    __syncthreads();
    for (int j = t; j < nb; j += 256)
        cur[j] = hist[j] ? atomicAdd(&bcur[j], hist[j]) : 0;
    __syncthreads();
#pragma unroll
    for (int k = 0; k < EPB_P / 256; ++k) {
        if (d[k] >= 0) {
            int pos = atomicAdd(&cur[d[k] >> LOGBS], 1);
            tmp[pos] = s[k] | ((d[k] & (BS - 1)) << 17);
        }
    }
}

// ---------------- build: per-bucket CSR slice in LDS; emits offs + norm ----

__global__ __launch_bounds__(256) void k_build(
    const int* __restrict__ tmp, const int* __restrict__ boff,
    int* __restrict__ csr, int* __restrict__ offs, float* __restrict__ norm,
    int n, int e)
{
    __shared__ int cnt[BS];
    __shared__ int ss[256];
    __shared__ int slice[CAP];   // 72 KB

    const int t = threadIdx.x;
    const int b = blockIdx.x;
    const int base_node = b << LOGBS;
    const int bo = boff[b];
    const int m = boff[b + 1] - bo;

    cnt[t] = 0; cnt[t + 256] = 0;
    __syncthreads();

    for (int i = t; i < m; i += 256)
        atomicAdd(&cnt[tmp[bo + i] >> 17], 1);
    __syncthreads();

    int c0 = cnt[2 * t], c1 = cnt[2 * t + 1];
    int loc = c0 + c1;
    ss[t] = loc;
    __syncthreads();
    for (int off = 1; off < 256; off <<= 1) {
        int u = (t >= off) ? ss[t - off] : 0;
        __syncthreads();
        ss[t] += u;
        __syncthreads();
    }
    int eb = ss[t] - loc;

    int n0 = base_node + 2 * t;
    if (n0 < n)     { offs[n0] = bo + eb;          norm[n0] = rsqrtf((float)c0 + 1.0f); }
    if (n0 + 1 < n) { offs[n0 + 1] = bo + eb + c0; norm[n0 + 1] = rsqrtf((float)c1 + 1.0f); }
    cnt[2 * t] = eb;
    cnt[2 * t + 1] = eb + c0;
    __syncthreads();

    for (int i = t; i < m; i += 256) {
        int p = tmp[bo + i];
        int pos = atomicAdd(&cnt[p >> 17], 1);
        if (pos < CAP) slice[pos] = p & 0x1FFFF;
    }
    __syncthreads();

    for (int i = t; i < m; i += 256) csr[bo + i] = slice[i];
}

// ---------------- GEMM1: {Hb0,Hb1} = fp16((x @ W1) * norm), feature-split --

__global__ __launch_bounds__(256) void k_gemm1(
    const float* __restrict__ x, const float* __restrict__ W1,
    const float* __restrict__ norm,
    __half* __restrict__ Hb0, __half* __restrict__ Hb1, int n)
{
    __shared__ float Wl[D_IN * H_DIM];   // 16 KB
    for (int i = threadIdx.x; i < D_IN * H_DIM; i += 256) Wl[i] = W1[i];
    __syncthreads();

    const int jg = threadIdx.x & 3;
    const int ns = threadIdx.x >> 2;
    const int n0 = blockIdx.x * 256 + ns * 4;
    const int j0 = jg * 8;

    float acc[4][8];
#pragma unroll
    for (int m = 0; m < 4; ++m)
#pragma unroll
        for (int j = 0; j < 8; ++j) acc[m][j] = 0.0f;

    for (int k = 0; k < D_IN; k += 4) {
        float4 xv[4];
#pragma unroll
        for (int m = 0; m < 4; ++m) {
            int nn = n0 + m;
            xv[m] = (nn < n) ? *(const float4*)&x[(size_t)nn * D_IN + k]
                             : make_float4(0.f, 0.f, 0.f, 0.f);
        }
#pragma unroll
        for (int kk = 0; kk < 4; ++kk) {
            const float4 wa = *(const float4*)&Wl[(k + kk) * H_DIM + j0];
            const float4 wb = *(const float4*)&Wl[(k + kk) * H_DIM + j0 + 4];
#pragma unroll
            for (int m = 0; m < 4; ++m) {
                const float xs = (kk == 0) ? xv[m].x : (kk == 1) ? xv[m].y
                               : (kk == 2) ? xv[m].z : xv[m].w;
                acc[m][0] = fmaf(xs, wa.x, acc[m][0]);
                acc[m][1] = fmaf(xs, wa.y, acc[m][1]);
                acc[m][2] = fmaf(xs, wa.z, acc[m][2]);
                acc[m][3] = fmaf(xs, wa.w, acc[m][3]);
                acc[m][4] = fmaf(xs, wb.x, acc[m][4]);
                acc[m][5] = fmaf(xs, wb.y, acc[m][5]);
                acc[m][6] = fmaf(xs, wb.z, acc[m][6]);
                acc[m][7] = fmaf(xs, wb.w, acc[m][7]);
            }
        }
    }

    __half* hout = (jg < 2) ? Hb0 : Hb1;
    const int jo = j0 & 15;
#pragma unroll
    for (int m = 0; m < 4; ++m) {
        int nn = n0 + m;
        if (nn < n) {
            float nr = norm[nn];
            uint4 pk;
            pk.x = h2u(__floats2half2_rn(acc[m][0]*nr, acc[m][1]*nr));
            pk.y = h2u(__floats2half2_rn(acc[m][2]*nr, acc[m][3]*nr));
            pk.z = h2u(__floats2half2_rn(acc[m][4]*nr, acc[m][5]*nr));
            pk.w = h2u(__floats2half2_rn(acc[m][6]*nr, acc[m][7]*nr));
            *(uint4*)&hout[(size_t)nn * 16 + jo] = pk;
        }
    }
}

// ---------------- GEMM2: {Hb0,Hb1} = fp16((relu(agg1+b1) @ W2) * norm) -----

__global__ __launch_bounds__(256) void k_gemm2(
    const float* __restrict__ agg1, const float* __restrict__ b1,
    const float* __restrict__ W2, const float* __restrict__ norm,
    __half* __restrict__ Hb0, __half* __restrict__ Hb1, int n)
{
    __shared__ float Wl[H_DIM * H_DIM];
    __shared__ float bl[H_DIM];
    for (int i = threadIdx.x; i < H_DIM * H_DIM; i += 256) Wl[i] = W2[i];
    if (threadIdx.x < H_DIM) bl[threadIdx.x] = b1[threadIdx.x];
    __syncthreads();

    const int jg = threadIdx.x & 3;
    const int ns = threadIdx.x >> 2;
    const int n0 = blockIdx.x * 256 + ns * 4;
    const int j0 = jg * 8;

    float acc[4][8];
#pragma unroll
    for (int m = 0; m < 4; ++m)
#pragma unroll
        for (int j = 0; j < 8; ++j) acc[m][j] = 0.0f;

    for (int k = 0; k < H_DIM; k += 4) {
        float4 xv[4];
#pragma unroll
        for (int m = 0; m < 4; ++m) {
            int nn = n0 + m;
            if (nn < n) {
                float4 v = *(const float4*)&agg1[(size_t)nn * H_DIM + k];
                v.x = fmaxf(v.x + bl[k + 0], 0.f);
                v.y = fmaxf(v.y + bl[k + 1], 0.f);
                v.z = fmaxf(v.z + bl[k + 2], 0.f);
                v.w = fmaxf(v.w + bl[k + 3], 0.f);
                xv[m] = v;
            } else {
                xv[m] = make_float4(0.f, 0.f, 0.f, 0.f);
            }
        }
#pragma unroll
        for (int kk = 0; kk < 4; ++kk) {
            const float4 wa = *(const float4*)&Wl[(k + kk) * H_DIM + j0];
            const float4 wb = *(const float4*)&Wl[(k + kk) * H_DIM + j0 + 4];
#pragma unroll
            for (int m = 0; m < 4; ++m) {
                const float xs = (kk == 0) ? xv[m].x : (kk == 1) ? xv[m].y
                               : (kk == 2) ? xv[m].z : xv[m].w;
                acc[m][0] = fmaf(xs, wa.x, acc[m][0]);
                acc[m][1] = fmaf(xs, wa.y, acc[m][1]);
                acc[m][2] = fmaf(xs, wa.z, acc[m][2]);
                acc[m][3] = fmaf(xs, wa.w, acc[m][3]);
                acc[m][4] = fmaf(xs, wb.x, acc[m][4]);
                acc[m][5] = fmaf(xs, wb.y, acc[m][5]);
                acc[m][6] = fmaf(xs, wb.z, acc[m][6]);
                acc[m][7] = fmaf(xs, wb.w, acc[m][7]);
            }
        }
    }

    __half* hout = (jg < 2) ? Hb0 : Hb1;
    const int jo = j0 & 15;
#pragma unroll
    for (int m = 0; m < 4; ++m) {
        int nn = n0 + m;
        if (nn < n) {
            float nr = norm[nn];
            uint4 pk;
            pk.x = h2u(__floats2half2_rn(acc[m][0]*nr, acc[m][1]*nr));
            pk.y = h2u(__floats2half2_rn(acc[m][2]*nr, acc[m][3]*nr));
            pk.z = h2u(__floats2half2_rn(acc[m][4]*nr, acc[m][5]*nr));
            pk.w = h2u(__floats2half2_rn(acc[m][6]*nr, acc[m][7]*nr));
            *(uint4*)&hout[(size_t)nn * 16 + jo] = pk;
        }
    }
}

// ---------------- gather (16-feature pass): wave per node, 16 edges x 4 lanes
// hs: n x 16 fp16 (3.2 MB -> per-XCD L2 resident). fp16 packed accumulation.

__global__ __launch_bounds__(256) void k_gath16(
    const __half* __restrict__ hs, const float* __restrict__ norm,
    const int* __restrict__ offs, const int* __restrict__ csr,
    float* __restrict__ agg, int n, int fbase)
{
    const int t = threadIdx.x;
    const int node = blockIdx.x * 4 + (t >> 6);
    if (node >= n) return;
    const int lane = t & 63;
    const int g = lane >> 2;        // 16 edge-groups
    const int q = lane & 3;         // 8B chunk within the 32B row

    const int beg = offs[node];
    const int end = offs[node + 1];
    const uint2* rows = (const uint2*)hs;   // 4 uint2 per row

    __half2 acc0 = u2h(0u), acc1 = u2h(0u);
    int j = beg + g;
    for (; j + 16 < end; j += 32) {
        int s0 = csr[j];
        int s1 = csr[j + 16];
        uint2 r0 = rows[s0 * 4 + q];
        uint2 r1 = rows[s1 * 4 + q];
        acc0 = __hadd2(acc0, __hadd2(u2h(r0.x), u2h(r1.x)));
        acc1 = __hadd2(acc1, __hadd2(u2h(r0.y), u2h(r1.y)));
    }
    if (j < end) {
        uint2 r0 = rows[csr[j] * 4 + q];
        acc0 = __hadd2(acc0, u2h(r0.x));
        acc1 = __hadd2(acc1, u2h(r0.y));
    }
    if (g == 0) {   // self-loop
        uint2 r0 = rows[node * 4 + q];
        acc0 = __hadd2(acc0, u2h(r0.x));
        acc1 = __hadd2(acc1, u2h(r0.y));
    }

#pragma unroll
    for (int o = 4; o < 64; o <<= 1) {
        acc0 = __hadd2(acc0, sh2(acc0, o));
        acc1 = __hadd2(acc1, sh2(acc1, o));
    }

    if (g == 0) {
        float nr = norm[node];
        float2 f0 = __half22float2(acc0);
        float2 f1 = __half22float2(acc1);
        *(float4*)&agg[(size_t)node * H_DIM + fbase + q * 4] =
            make_float4(f0.x * nr, f0.y * nr, f1.x * nr, f1.y * nr);
    }
}

// ---------------- final: out = sigmoid(relu(agg2 + b2) @ Wfc + bfc) --------

__global__ __launch_bounds__(256) void k_final(
    const float* __restrict__ agg2, const float* __restrict__ b2,
    const float* __restrict__ Wfc, const float* __restrict__ bfc,
    float* __restrict__ out, int n)
{
    __shared__ float Wl[H_DIM * OUT_DIM];
    __shared__ float bl[H_DIM];
    __shared__ float bfl[OUT_DIM];
    int t = threadIdx.x;
    if (t < H_DIM * OUT_DIM) Wl[t] = Wfc[t];
    if (t < H_DIM) bl[t] = b2[t];
    if (t < OUT_DIM) bfl[t] = bfc[t];
    __syncthreads();

    int i = blockIdx.x * 256 + t;
    if (i < n) {
        float a0 = bfl[0], a1 = bfl[1], a2 = bfl[2];
        const float* row = &agg2[(size_t)i * H_DIM];
#pragma unroll
        for (int j = 0; j < H_DIM; ++j) {
            float v = fmaxf(row[j] + bl[j], 0.f);
            a0 = fmaf(v, Wl[j * OUT_DIM + 0], a0);
            a1 = fmaf(v, Wl[j * OUT_DIM + 1], a1);
            a2 = fmaf(v, Wl[j * OUT_DIM + 2], a2);
        }
        out[(size_t)i * 3 + 0] = 1.0f / (1.0f + expf(-a0));
        out[(size_t)i * 3 + 1] = 1.0f / (1.0f + expf(-a1));
        out[(size_t)i * 3 + 2] = 1.0f / (1.0f + expf(-a2));
    }
}

// ---------------- launcher ----------------

extern "C" void kernel_launch(void* const* d_in, const int* in_sizes, int n_in,
                              void* d_out, int out_size, void* d_ws, size_t ws_size,
                              hipStream_t stream)
{
    const float* x   = (const float*)d_in[0];
    const int*   ei  = (const int*)d_in[1];
    const float* W1  = (const float*)d_in[2];
    const float* b1  = (const float*)d_in[3];
    const float* W2  = (const float*)d_in[4];
    const float* b2  = (const float*)d_in[5];
    const float* Wfc = (const float*)d_in[6];
    const float* bfc = (const float*)d_in[7];
    float* out = (float*)d_out;

    const int n = in_sizes[0] / D_IN;       // 100000  (< 2^17 for packing)
    const int e = in_sizes[1] / 2;          // 3200000
    const int* src = ei;
    const int* dst = ei + e;
    const int nb = (n + BS - 1) >> LOGBS;   // 196 buckets

    // ws layout (4B units):
    // norm[nAl] | offs[nAl] | bcnt[1024] | boff[1536] | bcur[1024] |
    // csr[eAl] | tmp[eAl] (aliases Hb0[n*16 fp16] + Hb1[n*16 fp16]) | R2[n*32]
    size_t nAl = ((size_t)n + 256) & ~(size_t)255;
    size_t eAl = ((size_t)e + 255) & ~(size_t)255;

    float* norm = (float*)d_ws;
    int*   offs = (int*)(norm + nAl);
    int*   bcnt = offs + nAl;
    int*   boff = bcnt + 1024;
    int*   bcur = boff + 1536;
    int*   csr  = bcur + 1024;
    int*   tmp  = csr + eAl;
    __half* Hb0 = (__half*)tmp;             // n x 16 fp16 (3.2 MB)
    __half* Hb1 = Hb0 + nAl * 16;           // n x 16 fp16 (3.2 MB)
    float* R2   = (float*)(tmp + eAl);      // agg1 / agg2 (f32 n x 32)

    const int nb_n = (n + 255) / 256;
    const int nb_c = (e + EPB - 1) / EPB;
    const int nb_p = (e + EPB_P - 1) / EPB_P;
    const int nb_g = (n + 3) / 4;

    // CSC build
    k_zero  <<<(nb + 255) / 256, 256, 0, stream>>>(bcnt, nb);
    k_bcount<<<nb_c, 256, 0, stream>>>(dst, bcnt, e, nb);
    k_bscan <<<1, 256, 0, stream>>>(bcnt, boff, bcur, offs, nb, n, e);
    k_part  <<<nb_p, 256, 0, stream>>>(src, dst, bcur, tmp, e, nb);
    k_build <<<nb, 256, 0, stream>>>(tmp, boff, csr, offs, norm, n, e);

    // layer 1: GEMM then two feature-half gather passes
    k_gemm1 <<<nb_n, 256, 0, stream>>>(x, W1, norm, Hb0, Hb1, n);
    k_gath16<<<nb_g, 256, 0, stream>>>(Hb0, norm, offs, csr, R2, n, 0);
    k_gath16<<<nb_g, 256, 0, stream>>>(Hb1, norm, offs, csr, R2, n, 16);

    // layer 2
    k_gemm2 <<<nb_n, 256, 0, stream>>>(R2, b1, W2, norm, Hb0, Hb1, n);
    k_gath16<<<nb_g, 256, 0, stream>>>(Hb0, norm, offs, csr, R2, n, 0);
    k_gath16<<<nb_g, 256, 0, stream>>>(Hb1, norm, offs, csr, R2, n, 16);

    // head
    k_final <<<nb_n, 256, 0, stream>>>(R2, b2, Wfc, bfc, out, n);
}

// Round 9
// 256.473 us; speedup vs baseline: 1.3046x; 1.3046x over previous
//
#include <hip/hip_runtime.h>
#include <hip/hip_fp16.h>
#include <math.h>

#define D_IN   128
#define H_DIM  32
#define OUT_DIM 3

#define BS      512          // nodes per bucket (pow2)
#define LOGBS   9
#define CAP     18432        // max edges per bucket slice in LDS
#define EPB     2048         // edges per block, k_bcount
#define EPB_P   4096         // edges per block, k_part
#define NB_MAX  1024

static __device__ inline unsigned int h2u(__half2 h) {
    union { __half2 h; unsigned int u; } c; c.h = h; return c.u;
}
static __device__ inline float2 u2f2(unsigned int u) {
    union { unsigned int u; __half2 h; } c; c.u = u;
    return __half22float2(c.h);
}

// ---------------- tiny zero ----------------

__global__ void k_zero(int* p, int n) {
    int i = blockIdx.x * blockDim.x + threadIdx.x;
    if (i < n) p[i] = 0;
}

// ---------------- bucket count ----------------

__global__ __launch_bounds__(256) void k_bcount(
    const int* __restrict__ dst, int* __restrict__ bcnt, int e, int nb)
{
    __shared__ int hist[NB_MAX];
    const int t = threadIdx.x;
    for (int j = t; j < nb; j += 256) hist[j] = 0;
    __syncthreads();
    const int base = blockIdx.x * EPB;
#pragma unroll
    for (int k = 0; k < EPB / 256; ++k) {
        int i = base + k * 256 + t;
        if (i < e) atomicAdd(&hist[dst[i] >> LOGBS], 1);
    }
    __syncthreads();
    for (int j = t; j < nb; j += 256)
        if (hist[j]) atomicAdd(&bcnt[j], hist[j]);
}

// ---------------- bucket scan (single block) ----------------

__global__ __launch_bounds__(256) void k_bscan(
    const int* __restrict__ bcnt, int* __restrict__ boff, int* __restrict__ bcur,
    int* __restrict__ offs, int nb, int n, int e)
{
    __shared__ int ss[256];
    const int t = threadIdx.x;
    int v[4];
    int loc = 0;
#pragma unroll
    for (int k = 0; k < 4; ++k) {
        int j = t * 4 + k;
        v[k] = (j < nb) ? bcnt[j] : 0;
        loc += v[k];
    }
    ss[t] = loc;
    __syncthreads();
    for (int off = 1; off < 256; off <<= 1) {
        int u = (t >= off) ? ss[t - off] : 0;
        __syncthreads();
        ss[t] += u;
        __syncthreads();
    }
    int base = ss[t] - loc;
#pragma unroll
    for (int k = 0; k < 4; ++k) {
        int j = t * 4 + k;
        if (j < nb) { boff[j] = base; bcur[j] = base; base += v[k]; }
    }
    if (t == 0) { boff[nb] = e; offs[n] = e; }
}

// ---------------- partition: packed edges into bucket regions ------
// pack = src | ((dst & (BS-1)) << 17)

__global__ __launch_bounds__(256) void k_part(
    const int* __restrict__ src, const int* __restrict__ dst,
    int* __restrict__ bcur, int* __restrict__ tmp, int e, int nb)
{
    __shared__ int hist[NB_MAX];
    __shared__ int cur[NB_MAX];
    const int t = threadIdx.x;
    for (int j = t; j < nb; j += 256) hist[j] = 0;
    __syncthreads();

    const int base = blockIdx.x * EPB_P;
    int d[EPB_P / 256], s[EPB_P / 256];
#pragma unroll
    for (int k = 0; k < EPB_P / 256; ++k) {
        int i = base + k * 256 + t;
        if (i < e) {
            d[k] = dst[i];
            s[k] = src[i];
            atomicAdd(&hist[d[k] >> LOGBS], 1);
        } else d[k] = -1;
    }
    __syncthreads();
    for (int j = t; j < nb; j += 256)
        cur[j] = hist[j] ? atomicAdd(&bcur[j], hist[j]) : 0;
    __syncthreads();
#pragma unroll
    for (int k = 0; k < EPB_P / 256; ++k) {
        if (d[k] >= 0) {
            int pos = atomicAdd(&cur[d[k] >> LOGBS], 1);
            tmp[pos] = s[k] | ((d[k] & (BS - 1)) << 17);
        }
    }
}

// ---------------- build: per-bucket CSR slice in LDS; emits offs + norm ----

__global__ __launch_bounds__(256) void k_build(
    const int* __restrict__ tmp, const int* __restrict__ boff,
    int* __restrict__ csr, int* __restrict__ offs, float* __restrict__ norm,
    int n, int e)
{
    __shared__ int cnt[BS];
    __shared__ int ss[256];
    __shared__ int slice[CAP];   // 72 KB

    const int t = threadIdx.x;
    const int b = blockIdx.x;
    const int base_node = b << LOGBS;
    const int bo = boff[b];
    const int m = boff[b + 1] - bo;

    cnt[t] = 0; cnt[t + 256] = 0;
    __syncthreads();

    for (int i = t; i < m; i += 256)
        atomicAdd(&cnt[tmp[bo + i] >> 17], 1);
    __syncthreads();

    int c0 = cnt[2 * t], c1 = cnt[2 * t + 1];
    int loc = c0 + c1;
    ss[t] = loc;
    __syncthreads();
    for (int off = 1; off < 256; off <<= 1) {
        int u = (t >= off) ? ss[t - off] : 0;
        __syncthreads();
        ss[t] += u;
        __syncthreads();
    }
    int eb = ss[t] - loc;

    int n0 = base_node + 2 * t;
    if (n0 < n)     { offs[n0] = bo + eb;          norm[n0] = rsqrtf((float)c0 + 1.0f); }
    if (n0 + 1 < n) { offs[n0 + 1] = bo + eb + c0; norm[n0 + 1] = rsqrtf((float)c1 + 1.0f); }
    cnt[2 * t] = eb;
    cnt[2 * t + 1] = eb + c0;
    __syncthreads();

    for (int i = t; i < m; i += 256) {
        int p = tmp[bo + i];
        int pos = atomicAdd(&cnt[p >> 17], 1);
        if (pos < CAP) slice[pos] = p & 0x1FFFF;
    }
    __syncthreads();

    for (int i = t; i < m; i += 256) csr[bo + i] = slice[i];
}

// ---------------- GEMM1: h1s = fp16((x @ W1) * norm) ----------------
// 64 nodes/block, thread = (node, 8-output group). 4 consecutive lanes read
// the same x float4 -> wave broadcast. Grid ~1563 blocks -> ~24 waves/CU.

__global__ __launch_bounds__(256) void k_gemm1(
    const float* __restrict__ x, const float* __restrict__ W1,
    const float* __restrict__ norm, __half* __restrict__ h1s, int n)
{
    __shared__ float Wl[D_IN * H_DIM];   // 16 KB
    for (int i = threadIdx.x; i < D_IN * H_DIM; i += 256) Wl[i] = W1[i];
    __syncthreads();

    const int t = threadIdx.x;
    const int jg = t & 3;
    const int node = blockIdx.x * 64 + (t >> 2);
    if (node >= n) return;
    const int j0 = jg * 8;

    float acc[8];
#pragma unroll
    for (int j = 0; j < 8; ++j) acc[j] = 0.0f;

    const float* xrow = &x[(size_t)node * D_IN];
    for (int k = 0; k < D_IN; k += 4) {
        const float4 xv = *(const float4*)&xrow[k];
#pragma unroll
        for (int kk = 0; kk < 4; ++kk) {
            const float xs = (kk == 0) ? xv.x : (kk == 1) ? xv.y
                           : (kk == 2) ? xv.z : xv.w;
            const float4 wa = *(const float4*)&Wl[(k + kk) * H_DIM + j0];
            const float4 wb = *(const float4*)&Wl[(k + kk) * H_DIM + j0 + 4];
            acc[0] = fmaf(xs, wa.x, acc[0]);
            acc[1] = fmaf(xs, wa.y, acc[1]);
            acc[2] = fmaf(xs, wa.z, acc[2]);
            acc[3] = fmaf(xs, wa.w, acc[3]);
            acc[4] = fmaf(xs, wb.x, acc[4]);
            acc[5] = fmaf(xs, wb.y, acc[5]);
            acc[6] = fmaf(xs, wb.z, acc[6]);
            acc[7] = fmaf(xs, wb.w, acc[7]);
        }
    }

    const float nr = norm[node];
    uint4 pk;
    pk.x = h2u(__floats2half2_rn(acc[0]*nr, acc[1]*nr));
    pk.y = h2u(__floats2half2_rn(acc[2]*nr, acc[3]*nr));
    pk.z = h2u(__floats2half2_rn(acc[4]*nr, acc[5]*nr));
    pk.w = h2u(__floats2half2_rn(acc[6]*nr, acc[7]*nr));
    *(uint4*)&h1s[(size_t)node * H_DIM + j0] = pk;
}

// ---------------- GEMM2: h2s = fp16((relu(agg1+b1) @ W2) * norm) -------
// same 64-nodes/block structure.

__global__ __launch_bounds__(256) void k_gemm2(
    const float* __restrict__ agg1, const float* __restrict__ b1,
    const float* __restrict__ W2, const float* __restrict__ norm,
    __half* __restrict__ h2s, int n)
{
    __shared__ float Wl[H_DIM * H_DIM];   // 4 KB
    __shared__ float bl[H_DIM];
    for (int i = threadIdx.x; i < H_DIM * H_DIM; i += 256) Wl[i] = W2[i];
    if (threadIdx.x < H_DIM) bl[threadIdx.x] = b1[threadIdx.x];
    __syncthreads();

    const int t = threadIdx.x;
    const int jg = t & 3;
    const int node = blockIdx.x * 64 + (t >> 2);
    if (node >= n) return;
    const int j0 = jg * 8;

    float acc[8];
#pragma unroll
    for (int j = 0; j < 8; ++j) acc[j] = 0.0f;

    const float* arow = &agg1[(size_t)node * H_DIM];
#pragma unroll
    for (int k = 0; k < H_DIM; k += 4) {
        float4 v = *(const float4*)&arow[k];
        v.x = fmaxf(v.x + bl[k + 0], 0.f);
        v.y = fmaxf(v.y + bl[k + 1], 0.f);
        v.z = fmaxf(v.z + bl[k + 2], 0.f);
        v.w = fmaxf(v.w + bl[k + 3], 0.f);
#pragma unroll
        for (int kk = 0; kk < 4; ++kk) {
            const float xs = (kk == 0) ? v.x : (kk == 1) ? v.y
                           : (kk == 2) ? v.z : v.w;
            const float4 wa = *(const float4*)&Wl[(k + kk) * H_DIM + j0];
            const float4 wb = *(const float4*)&Wl[(k + kk) * H_DIM + j0 + 4];
            acc[0] = fmaf(xs, wa.x, acc[0]);
            acc[1] = fmaf(xs, wa.y, acc[1]);
            acc[2] = fmaf(xs, wa.z, acc[2]);
            acc[3] = fmaf(xs, wa.w, acc[3]);
            acc[4] = fmaf(xs, wb.x, acc[4]);
            acc[5] = fmaf(xs, wb.y, acc[5]);
            acc[6] = fmaf(xs, wb.z, acc[6]);
            acc[7] = fmaf(xs, wb.w, acc[7]);
        }
    }

    const float nr = norm[node];
    uint4 pk;
    pk.x = h2u(__floats2half2_rn(acc[0]*nr, acc[1]*nr));
    pk.y = h2u(__floats2half2_rn(acc[2]*nr, acc[3]*nr));
    pk.z = h2u(__floats2half2_rn(acc[4]*nr, acc[5]*nr));
    pk.w = h2u(__floats2half2_rn(acc[6]*nr, acc[7]*nr));
    *(uint4*)&h2s[(size_t)node * H_DIM + j0] = pk;
}

// ---------------- gather: one wave per node, 8 edges x 8 lanes x 8B --------
// (R6 structure: best measured)

__global__ __launch_bounds__(256) void k_gather(
    const __half* __restrict__ hs, const float* __restrict__ norm,
    const int* __restrict__ offs, const int* __restrict__ csr,
    float* __restrict__ agg, int n)
{
    const int t = threadIdx.x;
    const int node = blockIdx.x * 4 + (t >> 6);
    if (node >= n) return;
    const int lane = t & 63;
    const int g = lane >> 3;
    const int q = lane & 7;

    const int beg = offs[node];
    const int end = offs[node + 1];
    const uint2* rows = (const uint2*)hs;   // row stride = 8 uint2

    float a0 = 0.f, a1 = 0.f, a2 = 0.f, a3 = 0.f;
    int j = beg + g;
    for (; j + 8 < end; j += 16) {
        int s0 = csr[j];
        int s1 = csr[j + 8];
        uint2 r0 = rows[s0 * 8 + q];
        uint2 r1 = rows[s1 * 8 + q];
        float2 u0 = u2f2(r0.x), u1 = u2f2(r0.y);
        float2 v0 = u2f2(r1.x), v1 = u2f2(r1.y);
        a0 += u0.x + v0.x; a1 += u0.y + v0.y;
        a2 += u1.x + v1.x; a3 += u1.y + v1.y;
    }
    if (j < end) {
        uint2 r0 = rows[csr[j] * 8 + q];
        float2 u0 = u2f2(r0.x), u1 = u2f2(r0.y);
        a0 += u0.x; a1 += u0.y; a2 += u1.x; a3 += u1.y;
    }
    if (g == 0) {   // self-loop
        uint2 r0 = rows[node * 8 + q];
        float2 u0 = u2f2(r0.x), u1 = u2f2(r0.y);
        a0 += u0.x; a1 += u0.y; a2 += u1.x; a3 += u1.y;
    }

#pragma unroll
    for (int o = 8; o < 64; o <<= 1) {
        a0 += __shfl_xor(a0, o); a1 += __shfl_xor(a1, o);
        a2 += __shfl_xor(a2, o); a3 += __shfl_xor(a3, o);
    }

    if (g == 0) {
        float nr = norm[node];
        *(float4*)&agg[(size_t)node * H_DIM + q * 4] =
            make_float4(a0 * nr, a1 * nr, a2 * nr, a3 * nr);
    }
}

// ---------------- gather2 + fused head -------------------------------------

__global__ __launch_bounds__(256) void k_gather_fin(
    const __half* __restrict__ hs, const float* __restrict__ norm,
    const int* __restrict__ offs, const int* __restrict__ csr,
    const float* __restrict__ b2, const float* __restrict__ Wfc,
    const float* __restrict__ bfc, float* __restrict__ out, int n)
{
    const int t = threadIdx.x;
    const int node = blockIdx.x * 4 + (t >> 6);
    if (node >= n) return;
    const int lane = t & 63;
    const int g = lane >> 3;
    const int q = lane & 7;

    const int beg = offs[node];
    const int end = offs[node + 1];
    const uint2* rows = (const uint2*)hs;

    float a0 = 0.f, a1 = 0.f, a2 = 0.f, a3 = 0.f;
    int j = beg + g;
    for (; j + 8 < end; j += 16) {
        int s0 = csr[j];
        int s1 = csr[j + 8];
        uint2 r0 = rows[s0 * 8 + q];
        uint2 r1 = rows[s1 * 8 + q];
        float2 u0 = u2f2(r0.x), u1 = u2f2(r0.y);
        float2 v0 = u2f2(r1.x), v1 = u2f2(r1.y);
        a0 += u0.x + v0.x; a1 += u0.y + v0.y;
        a2 += u1.x + v1.x; a3 += u1.y + v1.y;
    }
    if (j < end) {
        uint2 r0 = rows[csr[j] * 8 + q];
        float2 u0 = u2f2(r0.x), u1 = u2f2(r0.y);
        a0 += u0.x; a1 += u0.y; a2 += u1.x; a3 += u1.y;
    }
    if (g == 0) {   // self-loop
        uint2 r0 = rows[node * 8 + q];
        float2 u0 = u2f2(r0.x), u1 = u2f2(r0.y);
        a0 += u0.x; a1 += u0.y; a2 += u1.x; a3 += u1.y;
    }

#pragma unroll
    for (int o = 8; o < 64; o <<= 1) {
        a0 += __shfl_xor(a0, o); a1 += __shfl_xor(a1, o);
        a2 += __shfl_xor(a2, o); a3 += __shfl_xor(a3, o);
    }

    // fused head (all lanes compute; q selects the 4-feature slice)
    const float nr = norm[node];
    const int f = q * 4;
    float v0 = fmaxf(fmaf(a0, nr, b2[f + 0]), 0.f);
    float v1 = fmaxf(fmaf(a1, nr, b2[f + 1]), 0.f);
    float v2 = fmaxf(fmaf(a2, nr, b2[f + 2]), 0.f);
    float v3 = fmaxf(fmaf(a3, nr, b2[f + 3]), 0.f);
    float p0 = v0*Wfc[(f+0)*3+0] + v1*Wfc[(f+1)*3+0] + v2*Wfc[(f+2)*3+0] + v3*Wfc[(f+3)*3+0];
    float p1 = v0*Wfc[(f+0)*3+1] + v1*Wfc[(f+1)*3+1] + v2*Wfc[(f+2)*3+1] + v3*Wfc[(f+3)*3+1];
    float p2 = v0*Wfc[(f+0)*3+2] + v1*Wfc[(f+1)*3+2] + v2*Wfc[(f+2)*3+2] + v3*Wfc[(f+3)*3+2];
#pragma unroll
    for (int o = 1; o < 8; o <<= 1) {
        p0 += __shfl_xor(p0, o); p1 += __shfl_xor(p1, o); p2 += __shfl_xor(p2, o);
    }

    if (lane == 0) {
        out[(size_t)node * 3 + 0] = 1.0f / (1.0f + expf(-(p0 + bfc[0])));
        out[(size_t)node * 3 + 1] = 1.0f / (1.0f + expf(-(p1 + bfc[1])));
        out[(size_t)node * 3 + 2] = 1.0f / (1.0f + expf(-(p2 + bfc[2])));
    }
}

// ---------------- launcher ----------------

extern "C" void kernel_launch(void* const* d_in, const int* in_sizes, int n_in,
                              void* d_out, int out_size, void* d_ws, size_t ws_size,
                              hipStream_t stream)
{
    const float* x   = (const float*)d_in[0];
    const int*   ei  = (const int*)d_in[1];
    const float* W1  = (const float*)d_in[2];
    const float* b1  = (const float*)d_in[3];
    const float* W2  = (const float*)d_in[4];
    const float* b2  = (const float*)d_in[5];
    const float* Wfc = (const float*)d_in[6];
    const float* bfc = (const float*)d_in[7];
    float* out = (float*)d_out;

    const int n = in_sizes[0] / D_IN;       // 100000  (< 2^17 for packing)
    const int e = in_sizes[1] / 2;          // 3200000
    const int* src = ei;
    const int* dst = ei + e;
    const int nb = (n + BS - 1) >> LOGBS;   // 196 buckets

    // ws layout (4B units):
    // norm[nAl] | offs[nAl] | bcnt[1024] | boff[1536] | bcur[1024] |
    // csr[eAl] | tmp/Hb[eAl] | R2[n*32]
    size_t nAl = ((size_t)n + 256) & ~(size_t)255;
    size_t eAl = ((size_t)e + 255) & ~(size_t)255;

    float* norm = (float*)d_ws;
    int*   offs = (int*)(norm + nAl);
    int*   bcnt = offs + nAl;
    int*   boff = bcnt + 1024;
    int*   bcur = boff + 1536;
    int*   csr  = bcur + 1024;
    int*   tmp  = csr + eAl;
    __half* Hb  = (__half*)tmp;             // fp16 features, aliases dead tmp
    float* R2   = (float*)(tmp + eAl);      // agg1

    const int nb_gm = (n + 63) / 64;        // 1563 blocks for GEMMs
    const int nb_c = (e + EPB - 1) / EPB;
    const int nb_p = (e + EPB_P - 1) / EPB_P;
    const int nb_g = (n + 3) / 4;

    // CSC build
    k_zero  <<<(nb + 255) / 256, 256, 0, stream>>>(bcnt, nb);
    k_bcount<<<nb_c, 256, 0, stream>>>(dst, bcnt, e, nb);
    k_bscan <<<1, 256, 0, stream>>>(bcnt, boff, bcur, offs, nb, n, e);
    k_part  <<<nb_p, 256, 0, stream>>>(src, dst, bcur, tmp, e, nb);
    k_build <<<nb, 256, 0, stream>>>(tmp, boff, csr, offs, norm, n, e);

    // layer 1
    k_gemm1 <<<nb_gm, 256, 0, stream>>>(x, W1, norm, Hb, n);
    k_gather<<<nb_g, 256, 0, stream>>>(Hb, norm, offs, csr, R2, n);

    // layer 2 + fused head
    k_gemm2 <<<nb_gm, 256, 0, stream>>>(R2, b1, W2, norm, Hb, n);
    k_gather_fin<<<nb_g, 256, 0, stream>>>(Hb, norm, offs, csr, b2, Wfc, bfc, out, n);
}

// Round 10
// 225.763 us; speedup vs baseline: 1.4821x; 1.1360x over previous
//
#include <hip/hip_runtime.h>
#include <hip/hip_fp16.h>
#include <math.h>

#define D_IN   128
#define H_DIM  32
#define OUT_DIM 3

#define BS      512          // nodes per bucket (pow2)
#define LOGBS   9
#define CAP_B   17408        // strided capacity per bucket (mean 16326, +8.5 sigma)
#define EPB_P   4096         // edges per block, k_part
#define NB_MAX  1024

static __device__ inline unsigned int h2u(__half2 h) {
    union { __half2 h; unsigned int u; } c; c.h = h; return c.u;
}
static __device__ inline __half2 u2h(unsigned int u) {
    union { unsigned int u; __half2 h; } c; c.u = u; return c.h;
}
static __device__ inline __half2 sh2(__half2 v, int o) {
    return u2h((unsigned int)__shfl_xor((int)h2u(v), o));
}

// ---------------- cursor init: bcur[b] = b*CAP_B ----------------

__global__ void k_init_cur(int* bcur, int nb) {
    int i = threadIdx.x;
    if (i < nb) bcur[i] = i * CAP_B;
}

// ---------------- partition: packed edges into strided bucket regions ------
// pack = src | ((dst & (BS-1)) << 17)

__global__ __launch_bounds__(256) void k_part(
    const int* __restrict__ src, const int* __restrict__ dst,
    int* __restrict__ bcur, int* __restrict__ tmcsr, int e, int nb)
{
    __shared__ int hist[NB_MAX];
    __shared__ int cur[NB_MAX];
    const int t = threadIdx.x;
    for (int j = t; j < nb; j += 256) hist[j] = 0;
    __syncthreads();

    const int base = blockIdx.x * EPB_P;
    int d[EPB_P / 256], s[EPB_P / 256];
#pragma unroll
    for (int k = 0; k < EPB_P / 256; ++k) {
        int i = base + k * 256 + t;
        if (i < e) {
            d[k] = dst[i];
            s[k] = src[i];
            atomicAdd(&hist[d[k] >> LOGBS], 1);
        } else d[k] = -1;
    }
    __syncthreads();
    for (int j = t; j < nb; j += 256)
        cur[j] = hist[j] ? atomicAdd(&bcur[j], hist[j]) : 0;
    __syncthreads();
#pragma unroll
    for (int k = 0; k < EPB_P / 256; ++k) {
        if (d[k] >= 0) {
            int b = d[k] >> LOGBS;
            int pos = atomicAdd(&cur[b], 1);
            if (pos < (b + 1) * CAP_B)            // overflow guard (never in practice)
                tmcsr[pos] = s[k] | ((d[k] & (BS - 1)) << 17);
        }
    }
}

// ---------------- build: per-bucket CSR slice in LDS, IN PLACE -------------
// emits offs[], ends[], norm[].

__global__ __launch_bounds__(256) void k_build(
    int* __restrict__ tmcsr, const int* __restrict__ bcur,
    int* __restrict__ offs, int* __restrict__ ends, float* __restrict__ norm,
    int n)
{
    __shared__ int cnt[BS];
    __shared__ int ss[256];
    __shared__ int slice[CAP_B];   // 69.6 KB

    const int t = threadIdx.x;
    const int b = blockIdx.x;
    const int base_node = b << LOGBS;
    const int bo = b * CAP_B;
    int m = bcur[b] - bo;
    if (m > CAP_B) m = CAP_B;

    cnt[t] = 0; cnt[t + 256] = 0;
    __syncthreads();

    for (int i = t; i < m; i += 256)
        atomicAdd(&cnt[tmcsr[bo + i] >> 17], 1);
    __syncthreads();

    // exclusive scan of 512 counts (2 per thread)
    int c0 = cnt[2 * t], c1 = cnt[2 * t + 1];
    int loc = c0 + c1;
    ss[t] = loc;
    __syncthreads();
    for (int off = 1; off < 256; off <<= 1) {
        int u = (t >= off) ? ss[t - off] : 0;
        __syncthreads();
        ss[t] += u;
        __syncthreads();
    }
    int eb = ss[t] - loc;

    int n0 = base_node + 2 * t;
    if (n0 < n) {
        offs[n0] = bo + eb;
        ends[n0] = bo + eb + c0;
        norm[n0] = rsqrtf((float)c0 + 1.0f);
    }
    if (n0 + 1 < n) {
        offs[n0 + 1] = bo + eb + c0;
        ends[n0 + 1] = bo + eb + c0 + c1;
        norm[n0 + 1] = rsqrtf((float)c1 + 1.0f);
    }
    cnt[2 * t] = eb;
    cnt[2 * t + 1] = eb + c0;
    __syncthreads();

    for (int i = t; i < m; i += 256) {
        int p = tmcsr[bo + i];
        int pos = atomicAdd(&cnt[p >> 17], 1);
        if (pos < CAP_B) slice[pos] = p & 0x1FFFF;
    }
    __syncthreads();

    for (int i = t; i < m; i += 256) tmcsr[bo + i] = slice[i];   // in place
}

// ---------------- GEMM1: h1s = fp16((x @ W1) * norm) ----------------
// 64 nodes/block (R8 structure: occupancy-fixed).

__global__ __launch_bounds__(256) void k_gemm1(
    const float* __restrict__ x, const float* __restrict__ W1,
    const float* __restrict__ norm, __half* __restrict__ h1s, int n)
{
    __shared__ float Wl[D_IN * H_DIM];   // 16 KB
    for (int i = threadIdx.x; i < D_IN * H_DIM; i += 256) Wl[i] = W1[i];
    __syncthreads();

    const int t = threadIdx.x;
    const int jg = t & 3;
    const int node = blockIdx.x * 64 + (t >> 2);
    if (node >= n) return;
    const int j0 = jg * 8;

    float acc[8];
#pragma unroll
    for (int j = 0; j < 8; ++j) acc[j] = 0.0f;

    const float* xrow = &x[(size_t)node * D_IN];
    for (int k = 0; k < D_IN; k += 4) {
        const float4 xv = *(const float4*)&xrow[k];
#pragma unroll
        for (int kk = 0; kk < 4; ++kk) {
            const float xs = (kk == 0) ? xv.x : (kk == 1) ? xv.y
                           : (kk == 2) ? xv.z : xv.w;
            const float4 wa = *(const float4*)&Wl[(k + kk) * H_DIM + j0];
            const float4 wb = *(const float4*)&Wl[(k + kk) * H_DIM + j0 + 4];
            acc[0] = fmaf(xs, wa.x, acc[0]);
            acc[1] = fmaf(xs, wa.y, acc[1]);
            acc[2] = fmaf(xs, wa.z, acc[2]);
            acc[3] = fmaf(xs, wa.w, acc[3]);
            acc[4] = fmaf(xs, wb.x, acc[4]);
            acc[5] = fmaf(xs, wb.y, acc[5]);
            acc[6] = fmaf(xs, wb.z, acc[6]);
            acc[7] = fmaf(xs, wb.w, acc[7]);
        }
    }

    const float nr = norm[node];
    uint4 pk;
    pk.x = h2u(__floats2half2_rn(acc[0]*nr, acc[1]*nr));
    pk.y = h2u(__floats2half2_rn(acc[2]*nr, acc[3]*nr));
    pk.z = h2u(__floats2half2_rn(acc[4]*nr, acc[5]*nr));
    pk.w = h2u(__floats2half2_rn(acc[6]*nr, acc[7]*nr));
    *(uint4*)&h1s[(size_t)node * H_DIM + j0] = pk;
}

// ---------------- gather1 + fused GEMM2 ------------------------------------
// One wave per node; 8 edge-groups x 8 lanes x 8B; fp16 packed accumulation.
// After the feature reduce, lane (g,q) holds agg1 feats 4q..4q+3 (replicated);
// it computes GEMM2 partials for outputs 4g..4g+3 over its k-slice, reduces
// over q, and lanes q==0 write the fp16 h2 row.

__global__ __launch_bounds__(256) void k_gather_g2(
    const __half* __restrict__ hsA, const float* __restrict__ norm,
    const int* __restrict__ offs, const int* __restrict__ ends,
    const int* __restrict__ csr, const float* __restrict__ b1,
    const float* __restrict__ W2, __half* __restrict__ hsB, int n)
{
    __shared__ float Wl[H_DIM * H_DIM];   // W2[k][j]
    __shared__ float bl[H_DIM];
    for (int i = threadIdx.x; i < H_DIM * H_DIM; i += 256) Wl[i] = W2[i];
    if (threadIdx.x < H_DIM) bl[threadIdx.x] = b1[threadIdx.x];
    __syncthreads();

    const int t = threadIdx.x;
    const int node = blockIdx.x * 4 + (t >> 6);
    if (node >= n) return;
    const int lane = t & 63;
    const int g = lane >> 3;
    const int q = lane & 7;

    const int beg = offs[node];
    const int end = ends[node];
    const uint2* rows = (const uint2*)hsA;   // row stride = 8 uint2

    __half2 acc0 = u2h(0u), acc1 = u2h(0u);
    int j = beg + g;
    for (; j + 8 < end; j += 16) {
        int s0 = csr[j];
        int s1 = csr[j + 8];
        uint2 r0 = rows[s0 * 8 + q];
        uint2 r1 = rows[s1 * 8 + q];
        acc0 = __hadd2(acc0, __hadd2(u2h(r0.x), u2h(r1.x)));
        acc1 = __hadd2(acc1, __hadd2(u2h(r0.y), u2h(r1.y)));
    }
    if (j < end) {
        uint2 r0 = rows[csr[j] * 8 + q];
        acc0 = __hadd2(acc0, u2h(r0.x));
        acc1 = __hadd2(acc1, u2h(r0.y));
    }
    if (g == 0) {   // self-loop
        uint2 r0 = rows[node * 8 + q];
        acc0 = __hadd2(acc0, u2h(r0.x));
        acc1 = __hadd2(acc1, u2h(r0.y));
    }

#pragma unroll
    for (int o = 8; o < 64; o <<= 1) {
        acc0 = __hadd2(acc0, sh2(acc0, o));
        acc1 = __hadd2(acc1, sh2(acc1, o));
    }

    // agg1 k-slice -> relu(agg1 + b1)
    const float nr = norm[node];
    float2 f0 = __half22float2(acc0);
    float2 f1 = __half22float2(acc1);
    const int kb = q * 4;
    float u0 = fmaxf(fmaf(f0.x, nr, bl[kb + 0]), 0.f);
    float u1 = fmaxf(fmaf(f0.y, nr, bl[kb + 1]), 0.f);
    float u2 = fmaxf(fmaf(f1.x, nr, bl[kb + 2]), 0.f);
    float u3 = fmaxf(fmaf(f1.y, nr, bl[kb + 3]), 0.f);

    // GEMM2 partials for outputs 4g..4g+3
    float p[4];
#pragma unroll
    for (int jj = 0; jj < 4; ++jj) {
        int jc = 4 * g + jj;
        p[jj] = u0 * Wl[(kb + 0) * H_DIM + jc]
              + u1 * Wl[(kb + 1) * H_DIM + jc]
              + u2 * Wl[(kb + 2) * H_DIM + jc]
              + u3 * Wl[(kb + 3) * H_DIM + jc];
    }
#pragma unroll
    for (int o = 1; o < 8; o <<= 1) {
        p[0] += __shfl_xor(p[0], o); p[1] += __shfl_xor(p[1], o);
        p[2] += __shfl_xor(p[2], o); p[3] += __shfl_xor(p[3], o);
    }

    if (q == 0) {
        uint2 w;
        w.x = h2u(__floats2half2_rn(p[0] * nr, p[1] * nr));
        w.y = h2u(__floats2half2_rn(p[2] * nr, p[3] * nr));
        ((uint2*)hsB)[node * 8 + g] = w;
    }
}

// ---------------- gather2 + fused head -------------------------------------

__global__ __launch_bounds__(256) void k_gather_fin(
    const __half* __restrict__ hs, const float* __restrict__ norm,
    const int* __restrict__ offs, const int* __restrict__ ends,
    const int* __restrict__ csr, const float* __restrict__ b2,
    const float* __restrict__ Wfc, const float* __restrict__ bfc,
    float* __restrict__ out, int n)
{
    const int t = threadIdx.x;
    const int node = blockIdx.x * 4 + (t >> 6);
    if (node >= n) return;
    const int lane = t & 63;
    const int g = lane >> 3;
    const int q = lane & 7;

    const int beg = offs[node];
    const int end = ends[node];
    const uint2* rows = (const uint2*)hs;

    __half2 acc0 = u2h(0u), acc1 = u2h(0u);
    int j = beg + g;
    for (; j + 8 < end; j += 16) {
        int s0 = csr[j];
        int s1 = csr[j + 8];
        uint2 r0 = rows[s0 * 8 + q];
        uint2 r1 = rows[s1 * 8 + q];
        acc0 = __hadd2(acc0, __hadd2(u2h(r0.x), u2h(r1.x)));
        acc1 = __hadd2(acc1, __hadd2(u2h(r0.y), u2h(r1.y)));
    }
    if (j < end) {
        uint2 r0 = rows[csr[j] * 8 + q];
        acc0 = __hadd2(acc0, u2h(r0.x));
        acc1 = __hadd2(acc1, u2h(r0.y));
    }
    if (g == 0) {   // self-loop
        uint2 r0 = rows[node * 8 + q];
        acc0 = __hadd2(acc0, u2h(r0.x));
        acc1 = __hadd2(acc1, u2h(r0.y));
    }

#pragma unroll
    for (int o = 8; o < 64; o <<= 1) {
        acc0 = __hadd2(acc0, sh2(acc0, o));
        acc1 = __hadd2(acc1, sh2(acc1, o));
    }

    // fused head
    const float nr = norm[node];
    float2 f0 = __half22float2(acc0);
    float2 f1 = __half22float2(acc1);
    const int f = q * 4;
    float v0 = fmaxf(fmaf(f0.x, nr, b2[f + 0]), 0.f);
    float v1 = fmaxf(fmaf(f0.y, nr, b2[f + 1]), 0.f);
    float v2 = fmaxf(fmaf(f1.x, nr, b2[f + 2]), 0.f);
    float v3 = fmaxf(fmaf(f1.y, nr, b2[f + 3]), 0.f);
    float p0 = v0*Wfc[(f+0)*3+0] + v1*Wfc[(f+1)*3+0] + v2*Wfc[(f+2)*3+0] + v3*Wfc[(f+3)*3+0];
    float p1 = v0*Wfc[(f+0)*3+1] + v1*Wfc[(f+1)*3+1] + v2*Wfc[(f+2)*3+1] + v3*Wfc[(f+3)*3+1];
    float p2 = v0*Wfc[(f+0)*3+2] + v1*Wfc[(f+1)*3+2] + v2*Wfc[(f+2)*3+2] + v3*Wfc[(f+3)*3+2];
#pragma unroll
    for (int o = 1; o < 8; o <<= 1) {
        p0 += __shfl_xor(p0, o); p1 += __shfl_xor(p1, o); p2 += __shfl_xor(p2, o);
    }

    if (lane == 0) {
        out[(size_t)node * 3 + 0] = 1.0f / (1.0f + expf(-(p0 + bfc[0])));
        out[(size_t)node * 3 + 1] = 1.0f / (1.0f + expf(-(p1 + bfc[1])));
        out[(size_t)node * 3 + 2] = 1.0f / (1.0f + expf(-(p2 + bfc[2])));
    }
}

// ---------------- launcher ----------------

extern "C" void kernel_launch(void* const* d_in, const int* in_sizes, int n_in,
                              void* d_out, int out_size, void* d_ws, size_t ws_size,
                              hipStream_t stream)
{
    const float* x   = (const float*)d_in[0];
    const int*   ei  = (const int*)d_in[1];
    const float* W1  = (const float*)d_in[2];
    const float* b1  = (const float*)d_in[3];
    const float* W2  = (const float*)d_in[4];
    const float* b2  = (const float*)d_in[5];
    const float* Wfc = (const float*)d_in[6];
    const float* bfc = (const float*)d_in[7];
    float* out = (float*)d_out;

    const int n = in_sizes[0] / D_IN;       // 100000  (< 2^17 for packing)
    const int e = in_sizes[1] / 2;          // 3200000
    const int* src = ei;
    const int* dst = ei + e;
    const int nb = (n + BS - 1) >> LOGBS;   // 196 buckets

    // ws layout (4B units):
    // norm[nAl] | offs[nAl] | ends[nAl] | bcur[256] | tmcsr[nb*CAP_B] |
    // HbA[nAl*16] | HbB[nAl*16]        (~27.7 MB total)
    size_t nAl = ((size_t)n + 256) & ~(size_t)255;

    float* norm  = (float*)d_ws;
    int*   offs  = (int*)(norm + nAl);
    int*   ends  = offs + nAl;
    int*   bcur  = ends + nAl;
    int*   tmcsr = bcur + 256;
    __half* HbA  = (__half*)(tmcsr + (size_t)nb * CAP_B);
    __half* HbB  = HbA + nAl * H_DIM;

    const int nb_gm = (n + 63) / 64;        // 1563 blocks, GEMM1
    const int nb_p  = (e + EPB_P - 1) / EPB_P;
    const int nb_g  = (n + 3) / 4;

    // CSC build (strided buckets; no count/scan prepass)
    k_init_cur<<<1, 256, 0, stream>>>(bcur, nb);
    k_part <<<nb_p, 256, 0, stream>>>(src, dst, bcur, tmcsr, e, nb);
    k_build<<<nb, 256, 0, stream>>>(tmcsr, bcur, offs, ends, norm, n);

    // layer 1
    k_gemm1<<<nb_gm, 256, 0, stream>>>(x, W1, norm, HbA, n);

    // gather1 + GEMM2 fused
    k_gather_g2<<<nb_g, 256, 0, stream>>>(HbA, norm, offs, ends, tmcsr,
                                          b1, W2, HbB, n);

    // gather2 + head fused
    k_gather_fin<<<nb_g, 256, 0, stream>>>(HbB, norm, offs, ends, tmcsr,
                                           b2, Wfc, bfc, out, n);
}